// Round 1
// baseline (1197.930 us; speedup 1.0000x reference)
//
#include <hip/hip_runtime.h>
#include <hip/hip_bf16.h>
#include <math.h>

// GAT 3-layer forward, MI355X.
// Structure: per launch build CSR (dst-sorted) once; per batch run
// [GEMM+edge-logit epilogue] -> [CSR aggregate w/ segment softmax] x3 layers.

#define NEG_SLOPE 0.2f

constexpr int NN   = 50000;   // nodes
constexpr int FIN  = 128;     // input features
constexpr int HC   = 64;      // H*C for layers 1,2
constexpr int NCLS = 16;      // layer-3 output

// ---------------- CSR build ----------------

__global__ void init_deg_kernel(int* deg, int N) {
    int t = blockIdx.x * blockDim.x + threadIdx.x;
    if (t < N) deg[t] = 1;  // self-loop
}

__global__ void hist_kernel(const int* __restrict__ ei, int* deg, int E) {
    int t = blockIdx.x * blockDim.x + threadIdx.x;
    if (t < E) atomicAdd(&deg[ei[E + t]], 1);   // dst = ei[E + t]
}

__global__ __launch_bounds__(1024) void scan_kernel(const int* __restrict__ deg,
                                                    int* __restrict__ rp,
                                                    int* __restrict__ wp, int N) {
    __shared__ int buf[1024];
    __shared__ int carry;
    if (threadIdx.x == 0) carry = 0;
    __syncthreads();
    for (int base = 0; base < N; base += 1024) {
        int i = base + (int)threadIdx.x;
        int v = (i < N) ? deg[i] : 0;
        buf[threadIdx.x] = v;
        __syncthreads();
        for (int off = 1; off < 1024; off <<= 1) {
            int t = (threadIdx.x >= (unsigned)off) ? buf[threadIdx.x - off] : 0;
            __syncthreads();
            buf[threadIdx.x] += t;
            __syncthreads();
        }
        int incl = buf[threadIdx.x];
        int c = carry;
        if (i < N) { rp[i] = c + incl - v; wp[i] = c + incl - v; }
        __syncthreads();
        if (threadIdx.x == 0) carry = c + buf[1023];
        __syncthreads();
    }
    if (threadIdx.x == 0) rp[N] = carry;
}

__global__ void scatter_kernel(const int* __restrict__ ei, int* wp,
                               int* __restrict__ col, int E, int N) {
    int t = blockIdx.x * blockDim.x + threadIdx.x;
    int total = E + N;
    if (t >= total) return;
    if (t < E) {
        int s = ei[t];
        int d = ei[E + t];
        int pos = atomicAdd(&wp[d], 1);
        col[pos] = s;
    } else {
        int n = t - E;  // self-loop
        int pos = atomicAdd(&wp[n], 1);
        col[pos] = n;
    }
}

// ---------------- GEMM + edge-logit epilogue ----------------
// h = X @ W  (X: [N,K], W: [K,M]); e_src[n,hd] = sum_c h[n,hd,c]*a_src[hd,c]
// One wave handles 64/M nodes; lane = (sub, out-col).

template <int K, int M>
__global__ __launch_bounds__(256) void gemm_kernel(
    const float* __restrict__ X, const float* __restrict__ W,
    const float* __restrict__ as_, const float* __restrict__ ad_,
    float* __restrict__ Hout, float* __restrict__ Es, float* __restrict__ Ed,
    int N) {
    constexpr int NPW = 64 / M;   // nodes per wave
    constexpr int H = M / 16;
    __shared__ float xs[4][NPW * K];
    const int wave = threadIdx.x >> 6;
    const int lane = threadIdx.x & 63;
    const int gwave = blockIdx.x * 4 + wave;
    const int node0 = gwave * NPW;
    const bool active = node0 < N;
    if (active) {
        int rows = min(NPW, N - node0);
        int total = rows * K;
        const float* src = X + (size_t)node0 * K;
        for (int i = lane; i < total; i += 64) xs[wave][i] = src[i];
    }
    __syncthreads();
    if (!active) return;
    const int sub = lane / M;
    const int c = lane % M;
    const int node = node0 + sub;
    if (node >= N) return;
    const float* xrow = &xs[wave][sub * K];
    float acc = 0.f;
#pragma unroll
    for (int k = 0; k < K; k += 4) {
        float4 xv = *reinterpret_cast<const float4*>(&xrow[k]);
        acc = fmaf(xv.x, W[(k + 0) * M + c], acc);
        acc = fmaf(xv.y, W[(k + 1) * M + c], acc);
        acc = fmaf(xv.z, W[(k + 2) * M + c], acc);
        acc = fmaf(xv.w, W[(k + 3) * M + c], acc);
    }
    Hout[(size_t)node * M + c] = acc;
    const int hd = c >> 4;
    const int cc = c & 15;
    float ps = acc * as_[c];
    float pd = acc * ad_[c];
#pragma unroll
    for (int o = 8; o >= 1; o >>= 1) {
        ps += __shfl_xor(ps, o);
        pd += __shfl_xor(pd, o);
    }
    if (cc == 0) {
        Es[node * H + hd] = ps;
        Ed[node * H + hd] = pd;
    }
}

// ---------------- CSR aggregate with segment softmax ----------------
// thread t = n*H + hd. Two passes over in-edges: (1) max, (2) exp-sum +
// feature accumulate. out = acc/(denom+eps) + bias, optional relu.

template <int H, bool RELU>
__global__ __launch_bounds__(256) void aggregate_kernel(
    const int* __restrict__ rp, const int* __restrict__ col,
    const float* __restrict__ Hm, const float* __restrict__ Es,
    const float* __restrict__ Ed, const float* __restrict__ bias,
    float* __restrict__ Out, int N) {
    constexpr int C = 16;
    constexpr int M = H * C;
    int t = blockIdx.x * blockDim.x + threadIdx.x;
    if (t >= N * H) return;
    int n, hd;
    if (H == 1) { n = t; hd = 0; }
    else        { n = t >> 2; hd = t & 3; }
    const float ed = Ed[t];
    const int beg = rp[n], end = rp[n + 1];

    float m = -1e30f;
    for (int i = beg; i < end; ++i) {
        int s = col[i];
        float e = Es[s * H + hd] + ed;
        e = (e >= 0.f) ? e : NEG_SLOPE * e;
        m = fmaxf(m, e);
    }

    float denom = 0.f;
    float acc[C];
#pragma unroll
    for (int j = 0; j < C; ++j) acc[j] = 0.f;

    for (int i = beg; i < end; ++i) {
        int s = col[i];
        float e = Es[s * H + hd] + ed;
        e = (e >= 0.f) ? e : NEG_SLOPE * e;
        float ex = __expf(e - m);
        denom += ex;
        const float* hp = Hm + (size_t)s * M + hd * C;
        float4 h0 = *reinterpret_cast<const float4*>(hp + 0);
        float4 h1 = *reinterpret_cast<const float4*>(hp + 4);
        float4 h2 = *reinterpret_cast<const float4*>(hp + 8);
        float4 h3 = *reinterpret_cast<const float4*>(hp + 12);
        acc[0]  = fmaf(ex, h0.x, acc[0]);  acc[1]  = fmaf(ex, h0.y, acc[1]);
        acc[2]  = fmaf(ex, h0.z, acc[2]);  acc[3]  = fmaf(ex, h0.w, acc[3]);
        acc[4]  = fmaf(ex, h1.x, acc[4]);  acc[5]  = fmaf(ex, h1.y, acc[5]);
        acc[6]  = fmaf(ex, h1.z, acc[6]);  acc[7]  = fmaf(ex, h1.w, acc[7]);
        acc[8]  = fmaf(ex, h2.x, acc[8]);  acc[9]  = fmaf(ex, h2.y, acc[9]);
        acc[10] = fmaf(ex, h2.z, acc[10]); acc[11] = fmaf(ex, h2.w, acc[11]);
        acc[12] = fmaf(ex, h3.x, acc[12]); acc[13] = fmaf(ex, h3.y, acc[13]);
        acc[14] = fmaf(ex, h3.z, acc[14]); acc[15] = fmaf(ex, h3.w, acc[15]);
    }

    float inv = 1.f / (denom + 1e-16f);
    float* op = Out + (size_t)n * M + hd * C;
#pragma unroll
    for (int j = 0; j < C; ++j) {
        float v = fmaf(acc[j], inv, bias[hd * C + j]);
        if (RELU) v = fmaxf(v, 0.f);
        op[j] = v;
    }
}

// ---------------- launch ----------------

extern "C" void kernel_launch(void* const* d_in, const int* in_sizes, int n_in,
                              void* d_out, int out_size, void* d_ws, size_t ws_size,
                              hipStream_t stream) {
    const float* x   = (const float*)d_in[0];
    const int*   ei  = (const int*)d_in[1];
    const float* W1  = (const float*)d_in[2];
    const float* a1s = (const float*)d_in[3];
    const float* a1d = (const float*)d_in[4];
    const float* b1  = (const float*)d_in[5];
    const float* W2  = (const float*)d_in[6];
    const float* a2s = (const float*)d_in[7];
    const float* a2d = (const float*)d_in[8];
    const float* b2  = (const float*)d_in[9];
    const float* W3  = (const float*)d_in[10];
    const float* a3s = (const float*)d_in[11];
    const float* a3d = (const float*)d_in[12];
    const float* b3  = (const float*)d_in[13];
    float* outp = (float*)d_out;

    const int N  = NN;
    const int E  = in_sizes[1] / 2;
    const int ET = E + N;
    const int B  = in_sizes[0] / (N * FIN);

    char* ws = (char*)d_ws;
    size_t off = 0;
    auto alloc = [&](size_t bytes) -> void* {
        void* p = ws + off;
        off += (bytes + 255) & ~(size_t)255;
        return p;
    };
    int*   deg = (int*)alloc((size_t)N * 4);
    int*   rp  = (int*)alloc((size_t)(N + 1) * 4);
    int*   wp  = (int*)alloc((size_t)N * 4);
    int*   col = (int*)alloc((size_t)ET * 4);
    float* h   = (float*)alloc((size_t)N * HC * 4);
    float* z   = (float*)alloc((size_t)N * HC * 4);
    float* es  = (float*)alloc((size_t)N * 4 * 4);
    float* edv = (float*)alloc((size_t)N * 4 * 4);

    // CSR build (same graph for all batches/layers)
    init_deg_kernel<<<(N + 255) / 256, 256, 0, stream>>>(deg, N);
    hist_kernel<<<(E + 255) / 256, 256, 0, stream>>>(ei, deg, E);
    scan_kernel<<<1, 1024, 0, stream>>>(deg, rp, wp, N);
    scatter_kernel<<<(ET + 255) / 256, 256, 0, stream>>>(ei, wp, col, E, N);

    for (int b = 0; b < B; ++b) {
        const float* xb = x + (size_t)b * N * FIN;
        float* outb = outp + (size_t)b * N * NCLS;
        // layer 1: 128 -> 4x16
        gemm_kernel<128, 64><<<(N + 3) / 4, 256, 0, stream>>>(xb, W1, a1s, a1d, h, es, edv, N);
        aggregate_kernel<4, true><<<(N * 4 + 255) / 256, 256, 0, stream>>>(rp, col, h, es, edv, b1, z, N);
        // layer 2: 64 -> 4x16
        gemm_kernel<64, 64><<<(N + 3) / 4, 256, 0, stream>>>(z, W2, a2s, a2d, h, es, edv, N);
        aggregate_kernel<4, true><<<(N * 4 + 255) / 256, 256, 0, stream>>>(rp, col, h, es, edv, b2, z, N);
        // layer 3: 64 -> 1x16
        gemm_kernel<64, 16><<<(N + 15) / 16, 256, 0, stream>>>(z, W3, a3s, a3d, h, es, edv, N);
        aggregate_kernel<1, false><<<(N + 255) / 256, 256, 0, stream>>>(rp, col, h, es, edv, b3, outb, N);
    }
}

// Round 2
// 910.163 us; speedup vs baseline: 1.3162x; 1.3162x over previous
//
#include <hip/hip_runtime.h>
#include <hip/hip_bf16.h>
#include <math.h>

// GAT 3-layer forward, MI355X.
// CSR build (fast hierarchical scan) once; then per layer one batch-fused
// GEMM (+edge-logit epilogue) and one batch-fused single-pass online-softmax
// aggregate. Interleaved layouts: h[(n*B+b)*M + c], es[(n*B+b)*H + hd].

#define NEG_SLOPE 0.2f

constexpr int NN   = 50000;   // nodes
constexpr int FIN  = 128;     // input features
constexpr int HC   = 64;      // H*C for layers 1,2
constexpr int NCLS = 16;      // layer-3 output

// ---------------- CSR build ----------------

__global__ void init_deg_kernel(int* deg, int N) {
    int t = blockIdx.x * blockDim.x + threadIdx.x;
    if (t < N) deg[t] = 1;  // self-loop
}

__global__ void hist_kernel(const int* __restrict__ ei, int* deg, int E) {
    int t = blockIdx.x * blockDim.x + threadIdx.x;
    if (t < E) atomicAdd(&deg[ei[E + t]], 1);   // dst = ei[E + t]
}

// 3-level scan: per-block exclusive scan + block sums
__global__ __launch_bounds__(1024) void scan1_kernel(
    const int* __restrict__ deg, int* __restrict__ rp,
    int* __restrict__ bsum, int N) {
    __shared__ int buf[1024];
    int i = blockIdx.x * 1024 + threadIdx.x;
    int v = (i < N) ? deg[i] : 0;
    buf[threadIdx.x] = v;
    __syncthreads();
#pragma unroll
    for (int off = 1; off < 1024; off <<= 1) {
        int t = (threadIdx.x >= (unsigned)off) ? buf[threadIdx.x - off] : 0;
        __syncthreads();
        buf[threadIdx.x] += t;
        __syncthreads();
    }
    if (i < N) rp[i] = buf[threadIdx.x] - v;       // exclusive, block-local
    if (threadIdx.x == 1023) bsum[blockIdx.x] = buf[1023];
}

__global__ void scan2_kernel(int* __restrict__ bsum, int nb,
                             int* __restrict__ rp, int N) {
    int lane = threadIdx.x;  // single wave of 64; nb <= 64
    int v = (lane < nb) ? bsum[lane] : 0;
#pragma unroll
    for (int off = 1; off < 64; off <<= 1) {
        int t = __shfl_up(v, off);
        if (lane >= off) v += t;
    }
    if (lane < nb) bsum[lane] = v;   // inclusive
    if (lane == nb - 1) rp[N] = v;   // total
}

__global__ __launch_bounds__(1024) void scan3_kernel(
    int* __restrict__ rp, int* __restrict__ wp,
    const int* __restrict__ bsum, int N) {
    int i = blockIdx.x * 1024 + threadIdx.x;
    if (i >= N) return;
    int add = (blockIdx.x > 0) ? bsum[blockIdx.x - 1] : 0;
    int r = rp[i] + add;
    rp[i] = r;
    wp[i] = r;
}

__global__ void scatter_kernel(const int* __restrict__ ei, int* wp,
                               int* __restrict__ col, int E, int N) {
    int t = blockIdx.x * blockDim.x + threadIdx.x;
    int total = E + N;
    if (t >= total) return;
    if (t < E) {
        int s = ei[t];
        int d = ei[E + t];
        int pos = atomicAdd(&wp[d], 1);
        col[pos] = s;
    } else {
        int n = t - E;  // self-loop
        int pos = atomicAdd(&wp[n], 1);
        col[pos] = n;
    }
}

// ---------------- GEMM + edge-logit epilogue ----------------
// h = X @ W; e_src[n,hd] = sum_c h[n,hd,c]*a_src[hd,c]; batch b = blockIdx.y.
// IL: input X is interleaved [(n*BF+b)*K]; else batch-major [b*N*K + n*K].

template <int K, int M, int BF, bool IL>
__global__ __launch_bounds__(256) void gemm_kernel(
    const float* __restrict__ X, const float* __restrict__ W,
    const float* __restrict__ as_, const float* __restrict__ ad_,
    float* __restrict__ Hout, float* __restrict__ Es, float* __restrict__ Ed,
    int N) {
    constexpr int NPW = 64 / M;   // nodes per wave
    constexpr int H = M / 16;
    const int b = blockIdx.y;
    __shared__ float xs[4][NPW * K];
    const int wave = threadIdx.x >> 6;
    const int lane = threadIdx.x & 63;
    const int node0 = (blockIdx.x * 4 + wave) * NPW;
    if (node0 < N) {
        int rows = min(NPW, N - node0);
        for (int i = lane; i < rows * K; i += 64) {
            int r = i / K, k = i - r * K;
            int node = node0 + r;
            size_t src = IL ? ((size_t)node * BF + b) * K + k
                            : ((size_t)b * N + node) * K + k;
            xs[wave][i] = X[src];
        }
    }
    __syncthreads();
    if (node0 >= N) return;
    const int sub = lane / M;
    const int c = lane - sub * M;
    const int node = node0 + sub;
    if (node >= N) return;
    const float* xrow = &xs[wave][sub * K];
    float acc = 0.f;
#pragma unroll
    for (int k = 0; k < K; k += 4) {
        float4 xv = *reinterpret_cast<const float4*>(&xrow[k]);
        acc = fmaf(xv.x, W[(k + 0) * M + c], acc);
        acc = fmaf(xv.y, W[(k + 1) * M + c], acc);
        acc = fmaf(xv.z, W[(k + 2) * M + c], acc);
        acc = fmaf(xv.w, W[(k + 3) * M + c], acc);
    }
    Hout[((size_t)node * BF + b) * M + c] = acc;
    const int hd = c >> 4;
    const int cc = c & 15;
    float ps = acc * as_[c];
    float pd = acc * ad_[c];
#pragma unroll
    for (int o = 8; o >= 1; o >>= 1) {
        ps += __shfl_xor(ps, o);
        pd += __shfl_xor(pd, o);
    }
    if (cc == 0) {
        Es[((size_t)node * BF + b) * H + hd] = ps;
        Ed[((size_t)node * BF + b) * H + hd] = pd;
    }
}

// ---------------- single-pass online-softmax aggregate ----------------
// Thin threads: t -> (n, hd, b). One edge pass; online max with exact ex=1
// on the rescale path. out = acc/(denom+eps) + bias, optional relu.

template <int H, bool RELU, bool OUTB, int BF>
__global__ __launch_bounds__(256) void agg_kernel(
    const int* __restrict__ rp, const int* __restrict__ col,
    const float* __restrict__ Hm, const float* __restrict__ Es,
    const float* __restrict__ Ed, const float* __restrict__ bias,
    float* __restrict__ Out, int N) {
    constexpr int C = 16;
    constexpr int M = H * C;
    int t = blockIdx.x * 256 + threadIdx.x;
    if (t >= N * H * BF) return;
    int u = t;
    const int b  = u % BF; u /= BF;
    const int hd = u % H;  u /= H;
    const int n  = u;

    const float ed = Ed[((size_t)n * BF + b) * H + hd];
    const int beg = rp[n], end = rp[n + 1];

    float m = -1e30f, dn = 0.f;
    float acc[C];
#pragma unroll
    for (int j = 0; j < C; ++j) acc[j] = 0.f;

    for (int i = beg; i < end; ++i) {
        int s = col[i];
        float e = Es[((size_t)s * BF + b) * H + hd] + ed;
        e = (e >= 0.f) ? e : NEG_SLOPE * e;
        const float* hp = Hm + ((size_t)s * BF + b) * M + hd * C;
        float4 h0 = *reinterpret_cast<const float4*>(hp + 0);
        float4 h1 = *reinterpret_cast<const float4*>(hp + 4);
        float4 h2 = *reinterpret_cast<const float4*>(hp + 8);
        float4 h3 = *reinterpret_cast<const float4*>(hp + 12);
        if (e > m) {
            float sc = __expf(m - e);   // first iter: exp(-huge)=0
            m = e;
            dn = fmaf(dn, sc, 1.0f);    // ex = exp(e-m) = 1 exactly
            acc[0]=fmaf(acc[0],sc,h0.x);  acc[1]=fmaf(acc[1],sc,h0.y);
            acc[2]=fmaf(acc[2],sc,h0.z);  acc[3]=fmaf(acc[3],sc,h0.w);
            acc[4]=fmaf(acc[4],sc,h1.x);  acc[5]=fmaf(acc[5],sc,h1.y);
            acc[6]=fmaf(acc[6],sc,h1.z);  acc[7]=fmaf(acc[7],sc,h1.w);
            acc[8]=fmaf(acc[8],sc,h2.x);  acc[9]=fmaf(acc[9],sc,h2.y);
            acc[10]=fmaf(acc[10],sc,h2.z); acc[11]=fmaf(acc[11],sc,h2.w);
            acc[12]=fmaf(acc[12],sc,h3.x); acc[13]=fmaf(acc[13],sc,h3.y);
            acc[14]=fmaf(acc[14],sc,h3.z); acc[15]=fmaf(acc[15],sc,h3.w);
        } else {
            float ex = __expf(e - m);
            dn += ex;
            acc[0]=fmaf(ex,h0.x,acc[0]);  acc[1]=fmaf(ex,h0.y,acc[1]);
            acc[2]=fmaf(ex,h0.z,acc[2]);  acc[3]=fmaf(ex,h0.w,acc[3]);
            acc[4]=fmaf(ex,h1.x,acc[4]);  acc[5]=fmaf(ex,h1.y,acc[5]);
            acc[6]=fmaf(ex,h1.z,acc[6]);  acc[7]=fmaf(ex,h1.w,acc[7]);
            acc[8]=fmaf(ex,h2.x,acc[8]);  acc[9]=fmaf(ex,h2.y,acc[9]);
            acc[10]=fmaf(ex,h2.z,acc[10]); acc[11]=fmaf(ex,h2.w,acc[11]);
            acc[12]=fmaf(ex,h3.x,acc[12]); acc[13]=fmaf(ex,h3.y,acc[13]);
            acc[14]=fmaf(ex,h3.z,acc[14]); acc[15]=fmaf(ex,h3.w,acc[15]);
        }
    }

    float inv = 1.f / (dn + 1e-16f);
    const float* bp = bias + hd * C;
    float* op = OUTB ? (Out + ((size_t)b * N + n) * M + hd * C)
                     : (Out + ((size_t)n * BF + b) * M + hd * C);
    float vb[C];
#pragma unroll
    for (int j = 0; j < C; ++j) {
        float v = fmaf(acc[j], inv, bp[j]);
        if (RELU) v = fmaxf(v, 0.f);
        vb[j] = v;
    }
    *reinterpret_cast<float4*>(op + 0)  = make_float4(vb[0], vb[1], vb[2], vb[3]);
    *reinterpret_cast<float4*>(op + 4)  = make_float4(vb[4], vb[5], vb[6], vb[7]);
    *reinterpret_cast<float4*>(op + 8)  = make_float4(vb[8], vb[9], vb[10], vb[11]);
    *reinterpret_cast<float4*>(op + 12) = make_float4(vb[12], vb[13], vb[14], vb[15]);
}

// ---------------- launch ----------------

extern "C" void kernel_launch(void* const* d_in, const int* in_sizes, int n_in,
                              void* d_out, int out_size, void* d_ws, size_t ws_size,
                              hipStream_t stream) {
    const float* x   = (const float*)d_in[0];
    const int*   ei  = (const int*)d_in[1];
    const float* W1  = (const float*)d_in[2];
    const float* a1s = (const float*)d_in[3];
    const float* a1d = (const float*)d_in[4];
    const float* b1  = (const float*)d_in[5];
    const float* W2  = (const float*)d_in[6];
    const float* a2s = (const float*)d_in[7];
    const float* a2d = (const float*)d_in[8];
    const float* b2  = (const float*)d_in[9];
    const float* W3  = (const float*)d_in[10];
    const float* a3s = (const float*)d_in[11];
    const float* a3d = (const float*)d_in[12];
    const float* b3  = (const float*)d_in[13];
    float* outp = (float*)d_out;

    const int N  = NN;
    const int E  = in_sizes[1] / 2;
    const int ET = E + N;
    const int B  = in_sizes[0] / (N * FIN);
    const int NB1024 = (N + 1023) / 1024;

    char* ws = (char*)d_ws;
    size_t off = 0;
    auto alloc = [&](size_t bytes) -> void* {
        void* p = ws + off;
        off += (bytes + 255) & ~(size_t)255;
        return p;
    };
    int* deg  = (int*)alloc((size_t)N * 4);
    int* rp   = (int*)alloc((size_t)(N + 1) * 4);
    int* wp   = (int*)alloc((size_t)N * 4);
    int* bsum = (int*)alloc(64 * 4);
    int* col  = (int*)alloc((size_t)ET * 4);

    // fused (all-batch) path needs N*B*HC floats for h and z
    size_t fused_need = off + 2 * ((size_t)N * B * HC * 4 + 256)
                            + 2 * ((size_t)N * B * 4 * 4 + 256);
    bool fused = (B == 4) && (ws_size >= fused_need);
    int BF = fused ? 4 : 1;

    float* h   = (float*)alloc((size_t)N * BF * HC * 4);
    float* z   = (float*)alloc((size_t)N * BF * HC * 4);
    float* es  = (float*)alloc((size_t)N * BF * 4 * 4);
    float* edv = (float*)alloc((size_t)N * BF * 4 * 4);

    // CSR build (graph shared by all batches/layers)
    init_deg_kernel<<<(N + 255) / 256, 256, 0, stream>>>(deg, N);
    hist_kernel<<<(E + 255) / 256, 256, 0, stream>>>(ei, deg, E);
    scan1_kernel<<<NB1024, 1024, 0, stream>>>(deg, rp, bsum, N);
    scan2_kernel<<<1, 64, 0, stream>>>(bsum, NB1024, rp, N);
    scan3_kernel<<<NB1024, 1024, 0, stream>>>(rp, wp, bsum, N);
    scatter_kernel<<<(ET + 255) / 256, 256, 0, stream>>>(ei, wp, col, E, N);

    if (fused) {
        dim3 g12((N + 3) / 4, 4);
        dim3 g3((N + 15) / 16, 4);
        int agg12 = (N * 4 * 4 + 255) / 256;
        int agg3  = (N * 4 + 255) / 256;
        gemm_kernel<128, 64, 4, false><<<g12, 256, 0, stream>>>(x, W1, a1s, a1d, h, es, edv, N);
        agg_kernel<4, true, false, 4><<<agg12, 256, 0, stream>>>(rp, col, h, es, edv, b1, z, N);
        gemm_kernel<64, 64, 4, true><<<g12, 256, 0, stream>>>(z, W2, a2s, a2d, h, es, edv, N);
        agg_kernel<4, true, false, 4><<<agg12, 256, 0, stream>>>(rp, col, h, es, edv, b2, z, N);
        gemm_kernel<64, 16, 4, true><<<g3, 256, 0, stream>>>(z, W3, a3s, a3d, h, es, edv, N);
        agg_kernel<1, false, true, 4><<<agg3, 256, 0, stream>>>(rp, col, h, es, edv, b3, outp, N);
    } else {
        dim3 g12((N + 3) / 4, 1);
        dim3 g3((N + 15) / 16, 1);
        int agg12 = (N * 4 + 255) / 256;
        int agg3  = (N + 255) / 256;
        for (int b = 0; b < B; ++b) {
            const float* xb = x + (size_t)b * N * FIN;
            float* outb = outp + (size_t)b * N * NCLS;
            gemm_kernel<128, 64, 1, false><<<g12, 256, 0, stream>>>(xb, W1, a1s, a1d, h, es, edv, N);
            agg_kernel<4, true, false, 1><<<agg12, 256, 0, stream>>>(rp, col, h, es, edv, b1, z, N);
            gemm_kernel<64, 64, 1, false><<<g12, 256, 0, stream>>>(z, W2, a2s, a2d, h, es, edv, N);
            agg_kernel<4, true, false, 1><<<agg12, 256, 0, stream>>>(rp, col, h, es, edv, b2, z, N);
            gemm_kernel<64, 16, 1, false><<<g3, 256, 0, stream>>>(z, W3, a3s, a3d, h, es, edv, N);
            agg_kernel<1, false, false, 1><<<agg3, 256, 0, stream>>>(rp, col, h, es, edv, b3, outb, N);
        }
    }
}

// Round 3
// 719.241 us; speedup vs baseline: 1.6655x; 1.2654x over previous
//
#include <hip/hip_runtime.h>
#include <hip/hip_bf16.h>
#include <math.h>

// GAT 3-layer forward, MI355X.
// CSR build (hierarchical scan) once; per layer one batch-fused register-tiled
// GEMM (+edge-logit epilogue) and one batch-fused single-pass online-softmax
// aggregate. Interleaved layouts: h[(n*B+b)*M + c], es[(n*B+b)*H + hd].

#define NEG_SLOPE 0.2f

constexpr int NN   = 50000;   // nodes
constexpr int FIN  = 128;     // input features
constexpr int HC   = 64;      // H*C for layers 1,2
constexpr int NCLS = 16;      // layer-3 output

// ---------------- CSR build ----------------

__global__ void init_deg_kernel(int* deg, int N) {
    int t = blockIdx.x * blockDim.x + threadIdx.x;
    if (t < N) deg[t] = 1;  // self-loop
}

__global__ void hist_kernel(const int* __restrict__ ei, int* deg, int E) {
    int t = blockIdx.x * blockDim.x + threadIdx.x;
    if (t < E) atomicAdd(&deg[ei[E + t]], 1);   // dst = ei[E + t]
}

__global__ __launch_bounds__(1024) void scan1_kernel(
    const int* __restrict__ deg, int* __restrict__ rp,
    int* __restrict__ bsum, int N) {
    __shared__ int buf[1024];
    int i = blockIdx.x * 1024 + threadIdx.x;
    int v = (i < N) ? deg[i] : 0;
    buf[threadIdx.x] = v;
    __syncthreads();
#pragma unroll
    for (int off = 1; off < 1024; off <<= 1) {
        int t = (threadIdx.x >= (unsigned)off) ? buf[threadIdx.x - off] : 0;
        __syncthreads();
        buf[threadIdx.x] += t;
        __syncthreads();
    }
    if (i < N) rp[i] = buf[threadIdx.x] - v;       // exclusive, block-local
    if (threadIdx.x == 1023) bsum[blockIdx.x] = buf[1023];
}

__global__ void scan2_kernel(int* __restrict__ bsum, int nb,
                             int* __restrict__ rp, int N) {
    int lane = threadIdx.x;  // single wave; nb <= 64
    int v = (lane < nb) ? bsum[lane] : 0;
#pragma unroll
    for (int off = 1; off < 64; off <<= 1) {
        int t = __shfl_up(v, off);
        if (lane >= off) v += t;
    }
    if (lane < nb) bsum[lane] = v;   // inclusive
    if (lane == nb - 1) rp[N] = v;   // total
}

__global__ __launch_bounds__(1024) void scan3_kernel(
    int* __restrict__ rp, int* __restrict__ wp,
    const int* __restrict__ bsum, int N) {
    int i = blockIdx.x * 1024 + threadIdx.x;
    if (i >= N) return;
    int add = (blockIdx.x > 0) ? bsum[blockIdx.x - 1] : 0;
    int r = rp[i] + add;
    rp[i] = r;
    wp[i] = r;
}

__global__ void scatter_kernel(const int* __restrict__ ei, int* wp,
                               int* __restrict__ col, int E, int N) {
    int t = blockIdx.x * blockDim.x + threadIdx.x;
    int total = E + N;
    if (t >= total) return;
    if (t < E) {
        int s = ei[t];
        int d = ei[E + t];
        int pos = atomicAdd(&wp[d], 1);
        col[pos] = s;
    } else {
        int n = t - E;  // self-loop
        int pos = atomicAdd(&wp[n], 1);
        col[pos] = n;
    }
}

// ---------------- register-tiled GEMM + edge-logit epilogue ----------------
// h = X @ W; block computes NT nodes x M cols; thread owns RN x 4 acc block.
// W staged in LDS (conflict-free b128 reads); X read as float4 broadcasts
// straight from global (16 lanes share each address). Epilogue: per-head
// logit partial reduced over the 4 col-group lanes via shfl_xor.

template <int K, int M, int RN, int BF, bool IL>
__global__ __launch_bounds__(256) void gemm_kernel(
    const float* __restrict__ X, const float* __restrict__ W,
    const float* __restrict__ as_, const float* __restrict__ ad_,
    float* __restrict__ Hout, float* __restrict__ Es, float* __restrict__ Ed,
    int N) {
    constexpr int G  = M / 4;        // col groups per node (16 or 4)
    constexpr int NG = 256 / G;      // node groups per block
    constexpr int NT = NG * RN;      // nodes per block
    constexpr int H  = M / 16;
    __shared__ float Ws[K * M];
    const int b = blockIdx.y;
    const int t = threadIdx.x;
    for (int i = t; i < K * M / 4; i += 256)
        reinterpret_cast<float4*>(Ws)[i] = reinterpret_cast<const float4*>(W)[i];
    __syncthreads();

    const int cg = t % G;
    const int ng = t / G;
    const int c0 = cg * 4;
    const int node0 = blockIdx.x * NT + ng * RN;

    const float* xp[RN];
#pragma unroll
    for (int j = 0; j < RN; ++j) {
        int node = node0 + j;
        int nc = (node < N) ? node : 0;   // clamp; stores guarded below
        xp[j] = X + (IL ? ((size_t)nc * BF + b) * (size_t)K
                        : ((size_t)b * N + nc) * (size_t)K);
    }

    float acc[RN][4];
#pragma unroll
    for (int j = 0; j < RN; ++j)
#pragma unroll
        for (int cc = 0; cc < 4; ++cc) acc[j][cc] = 0.f;

#pragma unroll 4
    for (int k = 0; k < K; k += 4) {
        float4 w0 = *reinterpret_cast<const float4*>(&Ws[(k + 0) * M + c0]);
        float4 w1 = *reinterpret_cast<const float4*>(&Ws[(k + 1) * M + c0]);
        float4 w2 = *reinterpret_cast<const float4*>(&Ws[(k + 2) * M + c0]);
        float4 w3 = *reinterpret_cast<const float4*>(&Ws[(k + 3) * M + c0]);
#pragma unroll
        for (int j = 0; j < RN; ++j) {
            float4 xv = *reinterpret_cast<const float4*>(&xp[j][k]);
            acc[j][0] = fmaf(xv.x, w0.x, acc[j][0]);
            acc[j][1] = fmaf(xv.x, w0.y, acc[j][1]);
            acc[j][2] = fmaf(xv.x, w0.z, acc[j][2]);
            acc[j][3] = fmaf(xv.x, w0.w, acc[j][3]);
            acc[j][0] = fmaf(xv.y, w1.x, acc[j][0]);
            acc[j][1] = fmaf(xv.y, w1.y, acc[j][1]);
            acc[j][2] = fmaf(xv.y, w1.z, acc[j][2]);
            acc[j][3] = fmaf(xv.y, w1.w, acc[j][3]);
            acc[j][0] = fmaf(xv.z, w2.x, acc[j][0]);
            acc[j][1] = fmaf(xv.z, w2.y, acc[j][1]);
            acc[j][2] = fmaf(xv.z, w2.z, acc[j][2]);
            acc[j][3] = fmaf(xv.z, w2.w, acc[j][3]);
            acc[j][0] = fmaf(xv.w, w3.x, acc[j][0]);
            acc[j][1] = fmaf(xv.w, w3.y, acc[j][1]);
            acc[j][2] = fmaf(xv.w, w3.z, acc[j][2]);
            acc[j][3] = fmaf(xv.w, w3.w, acc[j][3]);
        }
    }

    const int hd = c0 >> 4;
    const float4 av = *reinterpret_cast<const float4*>(&as_[c0]);
    const float4 dv = *reinterpret_cast<const float4*>(&ad_[c0]);
#pragma unroll
    for (int j = 0; j < RN; ++j) {
        int node = node0 + j;
        float ps = acc[j][0] * av.x + acc[j][1] * av.y +
                   acc[j][2] * av.z + acc[j][3] * av.w;
        float pd = acc[j][0] * dv.x + acc[j][1] * dv.y +
                   acc[j][2] * dv.z + acc[j][3] * dv.w;
        ps += __shfl_xor(ps, 1); ps += __shfl_xor(ps, 2);
        pd += __shfl_xor(pd, 1); pd += __shfl_xor(pd, 2);
        if (node < N) {
            *reinterpret_cast<float4*>(&Hout[((size_t)node * BF + b) * M + c0]) =
                make_float4(acc[j][0], acc[j][1], acc[j][2], acc[j][3]);
            if ((cg & 3) == 0) {
                Es[((size_t)node * BF + b) * H + hd] = ps;
                Ed[((size_t)node * BF + b) * H + hd] = pd;
            }
        }
    }
}

// ---------------- single-pass online-softmax aggregate ----------------

template <int H, bool RELU, bool OUTB, int BF>
__global__ __launch_bounds__(256) void agg_kernel(
    const int* __restrict__ rp, const int* __restrict__ col,
    const float* __restrict__ Hm, const float* __restrict__ Es,
    const float* __restrict__ Ed, const float* __restrict__ bias,
    float* __restrict__ Out, int N) {
    constexpr int C = 16;
    constexpr int M = H * C;
    int t = blockIdx.x * 256 + threadIdx.x;
    if (t >= N * H * BF) return;
    int u = t;
    const int b  = u % BF; u /= BF;
    const int hd = u % H;  u /= H;
    const int n  = u;

    const float ed = Ed[((size_t)n * BF + b) * H + hd];
    const int beg = rp[n], end = rp[n + 1];

    float m = -1e30f, dn = 0.f;
    float acc[C];
#pragma unroll
    for (int j = 0; j < C; ++j) acc[j] = 0.f;

    for (int i = beg; i < end; ++i) {
        int s = col[i];
        float e = Es[((size_t)s * BF + b) * H + hd] + ed;
        e = (e >= 0.f) ? e : NEG_SLOPE * e;
        const float* hp = Hm + ((size_t)s * BF + b) * M + hd * C;
        float4 h0 = *reinterpret_cast<const float4*>(hp + 0);
        float4 h1 = *reinterpret_cast<const float4*>(hp + 4);
        float4 h2 = *reinterpret_cast<const float4*>(hp + 8);
        float4 h3 = *reinterpret_cast<const float4*>(hp + 12);
        if (e > m) {
            float sc = __expf(m - e);   // first iter: exp(-huge)=0
            m = e;
            dn = fmaf(dn, sc, 1.0f);    // ex = exp(e-m) = 1 exactly
            acc[0]=fmaf(acc[0],sc,h0.x);  acc[1]=fmaf(acc[1],sc,h0.y);
            acc[2]=fmaf(acc[2],sc,h0.z);  acc[3]=fmaf(acc[3],sc,h0.w);
            acc[4]=fmaf(acc[4],sc,h1.x);  acc[5]=fmaf(acc[5],sc,h1.y);
            acc[6]=fmaf(acc[6],sc,h1.z);  acc[7]=fmaf(acc[7],sc,h1.w);
            acc[8]=fmaf(acc[8],sc,h2.x);  acc[9]=fmaf(acc[9],sc,h2.y);
            acc[10]=fmaf(acc[10],sc,h2.z); acc[11]=fmaf(acc[11],sc,h2.w);
            acc[12]=fmaf(acc[12],sc,h3.x); acc[13]=fmaf(acc[13],sc,h3.y);
            acc[14]=fmaf(acc[14],sc,h3.z); acc[15]=fmaf(acc[15],sc,h3.w);
        } else {
            float ex = __expf(e - m);
            dn += ex;
            acc[0]=fmaf(ex,h0.x,acc[0]);  acc[1]=fmaf(ex,h0.y,acc[1]);
            acc[2]=fmaf(ex,h0.z,acc[2]);  acc[3]=fmaf(ex,h0.w,acc[3]);
            acc[4]=fmaf(ex,h1.x,acc[4]);  acc[5]=fmaf(ex,h1.y,acc[5]);
            acc[6]=fmaf(ex,h1.z,acc[6]);  acc[7]=fmaf(ex,h1.w,acc[7]);
            acc[8]=fmaf(ex,h2.x,acc[8]);  acc[9]=fmaf(ex,h2.y,acc[9]);
            acc[10]=fmaf(ex,h2.z,acc[10]); acc[11]=fmaf(ex,h2.w,acc[11]);
            acc[12]=fmaf(ex,h3.x,acc[12]); acc[13]=fmaf(ex,h3.y,acc[13]);
            acc[14]=fmaf(ex,h3.z,acc[14]); acc[15]=fmaf(ex,h3.w,acc[15]);
        }
    }

    float inv = 1.f / (dn + 1e-16f);
    const float* bp = bias + hd * C;
    float* op = OUTB ? (Out + ((size_t)b * N + n) * M + hd * C)
                     : (Out + ((size_t)n * BF + b) * M + hd * C);
    float vb[C];
#pragma unroll
    for (int j = 0; j < C; ++j) {
        float v = fmaf(acc[j], inv, bp[j]);
        if (RELU) v = fmaxf(v, 0.f);
        vb[j] = v;
    }
    *reinterpret_cast<float4*>(op + 0)  = make_float4(vb[0], vb[1], vb[2], vb[3]);
    *reinterpret_cast<float4*>(op + 4)  = make_float4(vb[4], vb[5], vb[6], vb[7]);
    *reinterpret_cast<float4*>(op + 8)  = make_float4(vb[8], vb[9], vb[10], vb[11]);
    *reinterpret_cast<float4*>(op + 12) = make_float4(vb[12], vb[13], vb[14], vb[15]);
}

// ---------------- launch ----------------

extern "C" void kernel_launch(void* const* d_in, const int* in_sizes, int n_in,
                              void* d_out, int out_size, void* d_ws, size_t ws_size,
                              hipStream_t stream) {
    const float* x   = (const float*)d_in[0];
    const int*   ei  = (const int*)d_in[1];
    const float* W1  = (const float*)d_in[2];
    const float* a1s = (const float*)d_in[3];
    const float* a1d = (const float*)d_in[4];
    const float* b1  = (const float*)d_in[5];
    const float* W2  = (const float*)d_in[6];
    const float* a2s = (const float*)d_in[7];
    const float* a2d = (const float*)d_in[8];
    const float* b2  = (const float*)d_in[9];
    const float* W3  = (const float*)d_in[10];
    const float* a3s = (const float*)d_in[11];
    const float* a3d = (const float*)d_in[12];
    const float* b3  = (const float*)d_in[13];
    float* outp = (float*)d_out;

    const int N  = NN;
    const int E  = in_sizes[1] / 2;
    const int ET = E + N;
    const int B  = in_sizes[0] / (N * FIN);
    const int NB1024 = (N + 1023) / 1024;

    char* ws = (char*)d_ws;
    size_t off = 0;
    auto alloc = [&](size_t bytes) -> void* {
        void* p = ws + off;
        off += (bytes + 255) & ~(size_t)255;
        return p;
    };
    int* deg  = (int*)alloc((size_t)N * 4);
    int* rp   = (int*)alloc((size_t)(N + 1) * 4);
    int* wp   = (int*)alloc((size_t)N * 4);
    int* bsum = (int*)alloc(64 * 4);
    int* col  = (int*)alloc((size_t)ET * 4);

    size_t fused_need = off + 2 * ((size_t)N * B * HC * 4 + 256)
                            + 2 * ((size_t)N * B * 4 * 4 + 256);
    bool fused = (B == 4) && (ws_size >= fused_need);
    int BF = fused ? 4 : 1;

    float* h   = (float*)alloc((size_t)N * BF * HC * 4);
    float* z   = (float*)alloc((size_t)N * BF * HC * 4);
    float* es  = (float*)alloc((size_t)N * BF * 4 * 4);
    float* edv = (float*)alloc((size_t)N * BF * 4 * 4);

    // CSR build (graph shared by all batches/layers)
    init_deg_kernel<<<(N + 255) / 256, 256, 0, stream>>>(deg, N);
    hist_kernel<<<(E + 255) / 256, 256, 0, stream>>>(ei, deg, E);
    scan1_kernel<<<NB1024, 1024, 0, stream>>>(deg, rp, bsum, N);
    scan2_kernel<<<1, 64, 0, stream>>>(bsum, NB1024, rp, N);
    scan3_kernel<<<NB1024, 1024, 0, stream>>>(rp, wp, bsum, N);
    scatter_kernel<<<(ET + 255) / 256, 256, 0, stream>>>(ei, wp, col, E, N);

    if (fused) {
        dim3 g12((N + 63) / 64, 4);     // NT=64 (RN=4, G=16)
        dim3 g3((N + 127) / 128, 4);    // NT=128 (RN=2, G=4)
        int agg12 = (N * 4 * 4 + 255) / 256;
        int agg3  = (N * 4 + 255) / 256;
        gemm_kernel<128, 64, 4, 4, false><<<g12, 256, 0, stream>>>(x, W1, a1s, a1d, h, es, edv, N);
        agg_kernel<4, true, false, 4><<<agg12, 256, 0, stream>>>(rp, col, h, es, edv, b1, z, N);
        gemm_kernel<64, 64, 4, 4, true><<<g12, 256, 0, stream>>>(z, W2, a2s, a2d, h, es, edv, N);
        agg_kernel<4, true, false, 4><<<agg12, 256, 0, stream>>>(rp, col, h, es, edv, b2, z, N);
        gemm_kernel<64, 16, 2, 4, true><<<g3, 256, 0, stream>>>(z, W3, a3s, a3d, h, es, edv, N);
        agg_kernel<1, false, true, 4><<<agg3, 256, 0, stream>>>(rp, col, h, es, edv, b3, outp, N);
    } else {
        dim3 g12((N + 63) / 64, 1);
        dim3 g3((N + 127) / 128, 1);
        int agg12 = (N * 4 + 255) / 256;
        int agg3  = (N + 255) / 256;
        for (int b = 0; b < B; ++b) {
            const float* xb = x + (size_t)b * N * FIN;
            float* outb = outp + (size_t)b * N * NCLS;
            gemm_kernel<128, 64, 4, 1, false><<<g12, 256, 0, stream>>>(xb, W1, a1s, a1d, h, es, edv, N);
            agg_kernel<4, true, false, 1><<<agg12, 256, 0, stream>>>(rp, col, h, es, edv, b1, z, N);
            gemm_kernel<64, 64, 4, 1, false><<<g12, 256, 0, stream>>>(z, W2, a2s, a2d, h, es, edv, N);
            agg_kernel<4, true, false, 1><<<agg12, 256, 0, stream>>>(rp, col, h, es, edv, b2, z, N);
            gemm_kernel<64, 16, 2, 1, false><<<g3, 256, 0, stream>>>(z, W3, a3s, a3d, h, es, edv, N);
            agg_kernel<1, false, false, 1><<<agg3, 256, 0, stream>>>(rp, col, h, es, edv, b3, outb, N);
        }
    }
}

// Round 4
// 580.026 us; speedup vs baseline: 2.0653x; 1.2400x over previous
//
#include <hip/hip_runtime.h>
#include <hip/hip_bf16.h>
#include <hip/hip_fp16.h>
#include <math.h>

// GAT 3-layer forward, MI355X.
// CSR build (hierarchical scan) once; per layer one batch-fused register-tiled
// GEMM (+edge-logit epilogue, fp16 h output) and one batch-fused single-pass
// online-softmax aggregate (fp16 h gather, depth-2 software pipeline).
// Interleaved layouts: h[(n*B+b)*M + c] (fp16), es[(n*B+b)*H + hd] (fp32).

#define NEG_SLOPE 0.2f

constexpr int NN   = 50000;   // nodes
constexpr int FIN  = 128;     // input features
constexpr int HC   = 64;      // H*C for layers 1,2
constexpr int NCLS = 16;      // layer-3 output

struct H16 { __half2 h[8]; };   // 16 fp16 = 32 B
struct H4  { __half2 h[2]; };   // 4 fp16 = 8 B

// ---------------- CSR build ----------------

__global__ void init_deg_kernel(int* deg, int N) {
    int t = blockIdx.x * blockDim.x + threadIdx.x;
    if (t < N) deg[t] = 1;  // self-loop
}

__global__ void hist_kernel(const int* __restrict__ ei, int* deg, int E) {
    int t = blockIdx.x * blockDim.x + threadIdx.x;
    if (t < E) atomicAdd(&deg[ei[E + t]], 1);   // dst = ei[E + t]
}

__global__ __launch_bounds__(1024) void scan1_kernel(
    const int* __restrict__ deg, int* __restrict__ rp,
    int* __restrict__ bsum, int N) {
    __shared__ int buf[1024];
    int i = blockIdx.x * 1024 + threadIdx.x;
    int v = (i < N) ? deg[i] : 0;
    buf[threadIdx.x] = v;
    __syncthreads();
#pragma unroll
    for (int off = 1; off < 1024; off <<= 1) {
        int t = (threadIdx.x >= (unsigned)off) ? buf[threadIdx.x - off] : 0;
        __syncthreads();
        buf[threadIdx.x] += t;
        __syncthreads();
    }
    if (i < N) rp[i] = buf[threadIdx.x] - v;       // exclusive, block-local
    if (threadIdx.x == 1023) bsum[blockIdx.x] = buf[1023];
}

__global__ void scan2_kernel(int* __restrict__ bsum, int nb,
                             int* __restrict__ rp, int N) {
    int lane = threadIdx.x;  // single wave; nb <= 64
    int v = (lane < nb) ? bsum[lane] : 0;
#pragma unroll
    for (int off = 1; off < 64; off <<= 1) {
        int t = __shfl_up(v, off);
        if (lane >= off) v += t;
    }
    if (lane < nb) bsum[lane] = v;   // inclusive
    if (lane == nb - 1) rp[N] = v;   // total
}

__global__ __launch_bounds__(1024) void scan3_kernel(
    int* __restrict__ rp, int* __restrict__ wp,
    const int* __restrict__ bsum, int N) {
    int i = blockIdx.x * 1024 + threadIdx.x;
    if (i >= N) return;
    int add = (blockIdx.x > 0) ? bsum[blockIdx.x - 1] : 0;
    int r = rp[i] + add;
    rp[i] = r;
    wp[i] = r;
}

__global__ void scatter_kernel(const int* __restrict__ ei, int* wp,
                               int* __restrict__ col, int E, int N) {
    int t = blockIdx.x * blockDim.x + threadIdx.x;
    int total = E + N;
    if (t >= total) return;
    if (t < E) {
        int s = ei[t];
        int d = ei[E + t];
        int pos = atomicAdd(&wp[d], 1);
        col[pos] = s;
    } else {
        int n = t - E;  // self-loop
        int pos = atomicAdd(&wp[n], 1);
        col[pos] = n;
    }
}

// ---------------- register-tiled GEMM + edge-logit epilogue ----------------
// h = X @ W; block computes NT nodes x M cols; thread owns RN x 4 acc block.
// W staged in LDS; X read as float4 broadcasts from global. Hout in fp16.

template <int K, int M, int RN, int BF, bool IL>
__global__ __launch_bounds__(256) void gemm_kernel(
    const float* __restrict__ X, const float* __restrict__ W,
    const float* __restrict__ as_, const float* __restrict__ ad_,
    __half* __restrict__ Hout, float* __restrict__ Es, float* __restrict__ Ed,
    int N) {
    constexpr int G  = M / 4;        // col groups per node (16 or 4)
    constexpr int NG = 256 / G;      // node groups per block
    constexpr int NT = NG * RN;      // nodes per block
    constexpr int H  = M / 16;
    __shared__ float Ws[K * M];
    const int b = blockIdx.y;
    const int t = threadIdx.x;
    for (int i = t; i < K * M / 4; i += 256)
        reinterpret_cast<float4*>(Ws)[i] = reinterpret_cast<const float4*>(W)[i];
    __syncthreads();

    const int cg = t % G;
    const int ng = t / G;
    const int c0 = cg * 4;
    const int node0 = blockIdx.x * NT + ng * RN;

    const float* xp[RN];
#pragma unroll
    for (int j = 0; j < RN; ++j) {
        int node = node0 + j;
        int nc = (node < N) ? node : 0;   // clamp; stores guarded below
        xp[j] = X + (IL ? ((size_t)nc * BF + b) * (size_t)K
                        : ((size_t)b * N + nc) * (size_t)K);
    }

    float acc[RN][4];
#pragma unroll
    for (int j = 0; j < RN; ++j)
#pragma unroll
        for (int cc = 0; cc < 4; ++cc) acc[j][cc] = 0.f;

#pragma unroll 4
    for (int k = 0; k < K; k += 4) {
        float4 w0 = *reinterpret_cast<const float4*>(&Ws[(k + 0) * M + c0]);
        float4 w1 = *reinterpret_cast<const float4*>(&Ws[(k + 1) * M + c0]);
        float4 w2 = *reinterpret_cast<const float4*>(&Ws[(k + 2) * M + c0]);
        float4 w3 = *reinterpret_cast<const float4*>(&Ws[(k + 3) * M + c0]);
#pragma unroll
        for (int j = 0; j < RN; ++j) {
            float4 xv = *reinterpret_cast<const float4*>(&xp[j][k]);
            acc[j][0] = fmaf(xv.x, w0.x, acc[j][0]);
            acc[j][1] = fmaf(xv.x, w0.y, acc[j][1]);
            acc[j][2] = fmaf(xv.x, w0.z, acc[j][2]);
            acc[j][3] = fmaf(xv.x, w0.w, acc[j][3]);
            acc[j][0] = fmaf(xv.y, w1.x, acc[j][0]);
            acc[j][1] = fmaf(xv.y, w1.y, acc[j][1]);
            acc[j][2] = fmaf(xv.y, w1.z, acc[j][2]);
            acc[j][3] = fmaf(xv.y, w1.w, acc[j][3]);
            acc[j][0] = fmaf(xv.z, w2.x, acc[j][0]);
            acc[j][1] = fmaf(xv.z, w2.y, acc[j][1]);
            acc[j][2] = fmaf(xv.z, w2.z, acc[j][2]);
            acc[j][3] = fmaf(xv.z, w2.w, acc[j][3]);
            acc[j][0] = fmaf(xv.w, w3.x, acc[j][0]);
            acc[j][1] = fmaf(xv.w, w3.y, acc[j][1]);
            acc[j][2] = fmaf(xv.w, w3.z, acc[j][2]);
            acc[j][3] = fmaf(xv.w, w3.w, acc[j][3]);
        }
    }

    const int hd = c0 >> 4;
    const float4 av = *reinterpret_cast<const float4*>(&as_[c0]);
    const float4 dv = *reinterpret_cast<const float4*>(&ad_[c0]);
#pragma unroll
    for (int j = 0; j < RN; ++j) {
        int node = node0 + j;
        float ps = acc[j][0] * av.x + acc[j][1] * av.y +
                   acc[j][2] * av.z + acc[j][3] * av.w;
        float pd = acc[j][0] * dv.x + acc[j][1] * dv.y +
                   acc[j][2] * dv.z + acc[j][3] * dv.w;
        ps += __shfl_xor(ps, 1); ps += __shfl_xor(ps, 2);
        pd += __shfl_xor(pd, 1); pd += __shfl_xor(pd, 2);
        if (node < N) {
            H4 hv;
            hv.h[0] = __float22half2_rn(make_float2(acc[j][0], acc[j][1]));
            hv.h[1] = __float22half2_rn(make_float2(acc[j][2], acc[j][3]));
            *reinterpret_cast<H4*>(&Hout[((size_t)node * BF + b) * M + c0]) = hv;
            if ((cg & 3) == 0) {
                Es[((size_t)node * BF + b) * H + hd] = ps;
                Ed[((size_t)node * BF + b) * H + hd] = pd;
            }
        }
    }
}

// ---------------- single-pass online-softmax aggregate ----------------
// Thin threads: t -> (n, hd, b). Depth-2 software pipeline: issue edge i+1
// loads (col/Es/h16) before computing edge i's exp+fma.

template <int H, bool RELU, bool OUTB, int BF>
__global__ __launch_bounds__(256) void agg_kernel(
    const int* __restrict__ rp, const int* __restrict__ col,
    const __half* __restrict__ Hm, const float* __restrict__ Es,
    const float* __restrict__ Ed, const float* __restrict__ bias,
    float* __restrict__ Out, int N) {
    constexpr int C = 16;
    constexpr int M = H * C;
    int t = blockIdx.x * 256 + threadIdx.x;
    if (t >= N * H * BF) return;
    int u = t;
    const int b  = u % BF; u /= BF;
    const int hd = u % H;  u /= H;
    const int n  = u;

    const float ed = Ed[((size_t)n * BF + b) * H + hd];
    const int beg = rp[n], end = rp[n + 1];

    float m = -1e30f, dn = 0.f;
    float acc[C];
#pragma unroll
    for (int j = 0; j < C; ++j) acc[j] = 0.f;

    // prologue: load edge `beg` (degree >= 1 always: self-loop)
    int i = beg;
    int sA = col[i];
    float esA = Es[((size_t)sA * BF + b) * H + hd];
    H16 hA = *reinterpret_cast<const H16*>(Hm + ((size_t)sA * BF + b) * M + hd * C);

    while (true) {
        // issue next edge's loads before computing current
        int inext = i + 1;
        bool more = (inext < end);
        int sB = 0; float esB = 0.f; H16 hB;
        if (more) {
            sB = col[inext];
            esB = Es[((size_t)sB * BF + b) * H + hd];
            hB = *reinterpret_cast<const H16*>(Hm + ((size_t)sB * BF + b) * M + hd * C);
        }

        float e = esA + ed;
        e = (e >= 0.f) ? e : NEG_SLOPE * e;
        float2 f0 = __half22float2(hA.h[0]);
        float2 f1 = __half22float2(hA.h[1]);
        float2 f2 = __half22float2(hA.h[2]);
        float2 f3 = __half22float2(hA.h[3]);
        float2 f4 = __half22float2(hA.h[4]);
        float2 f5 = __half22float2(hA.h[5]);
        float2 f6 = __half22float2(hA.h[6]);
        float2 f7 = __half22float2(hA.h[7]);
        if (e > m) {
            float sc = __expf(m - e);   // first iter: exp(-huge)=0
            m = e;
            dn = fmaf(dn, sc, 1.0f);    // ex = exp(e-m) = 1 exactly
            acc[0]=fmaf(acc[0],sc,f0.x);   acc[1]=fmaf(acc[1],sc,f0.y);
            acc[2]=fmaf(acc[2],sc,f1.x);   acc[3]=fmaf(acc[3],sc,f1.y);
            acc[4]=fmaf(acc[4],sc,f2.x);   acc[5]=fmaf(acc[5],sc,f2.y);
            acc[6]=fmaf(acc[6],sc,f3.x);   acc[7]=fmaf(acc[7],sc,f3.y);
            acc[8]=fmaf(acc[8],sc,f4.x);   acc[9]=fmaf(acc[9],sc,f4.y);
            acc[10]=fmaf(acc[10],sc,f5.x); acc[11]=fmaf(acc[11],sc,f5.y);
            acc[12]=fmaf(acc[12],sc,f6.x); acc[13]=fmaf(acc[13],sc,f6.y);
            acc[14]=fmaf(acc[14],sc,f7.x); acc[15]=fmaf(acc[15],sc,f7.y);
        } else {
            float ex = __expf(e - m);
            dn += ex;
            acc[0]=fmaf(ex,f0.x,acc[0]);   acc[1]=fmaf(ex,f0.y,acc[1]);
            acc[2]=fmaf(ex,f1.x,acc[2]);   acc[3]=fmaf(ex,f1.y,acc[3]);
            acc[4]=fmaf(ex,f2.x,acc[4]);   acc[5]=fmaf(ex,f2.y,acc[5]);
            acc[6]=fmaf(ex,f3.x,acc[6]);   acc[7]=fmaf(ex,f3.y,acc[7]);
            acc[8]=fmaf(ex,f4.x,acc[8]);   acc[9]=fmaf(ex,f4.y,acc[9]);
            acc[10]=fmaf(ex,f5.x,acc[10]); acc[11]=fmaf(ex,f5.y,acc[11]);
            acc[12]=fmaf(ex,f6.x,acc[12]); acc[13]=fmaf(ex,f6.y,acc[13]);
            acc[14]=fmaf(ex,f7.x,acc[14]); acc[15]=fmaf(ex,f7.y,acc[15]);
        }
        if (!more) break;
        i = inext; sA = sB; esA = esB; hA = hB;
    }

    float inv = 1.f / (dn + 1e-16f);
    const float* bp = bias + hd * C;
    float* op = OUTB ? (Out + ((size_t)b * N + n) * M + hd * C)
                     : (Out + ((size_t)n * BF + b) * M + hd * C);
    float vb[C];
#pragma unroll
    for (int j = 0; j < C; ++j) {
        float v = fmaf(acc[j], inv, bp[j]);
        if (RELU) v = fmaxf(v, 0.f);
        vb[j] = v;
    }
    *reinterpret_cast<float4*>(op + 0)  = make_float4(vb[0], vb[1], vb[2], vb[3]);
    *reinterpret_cast<float4*>(op + 4)  = make_float4(vb[4], vb[5], vb[6], vb[7]);
    *reinterpret_cast<float4*>(op + 8)  = make_float4(vb[8], vb[9], vb[10], vb[11]);
    *reinterpret_cast<float4*>(op + 12) = make_float4(vb[12], vb[13], vb[14], vb[15]);
}

// ---------------- launch ----------------

extern "C" void kernel_launch(void* const* d_in, const int* in_sizes, int n_in,
                              void* d_out, int out_size, void* d_ws, size_t ws_size,
                              hipStream_t stream) {
    const float* x   = (const float*)d_in[0];
    const int*   ei  = (const int*)d_in[1];
    const float* W1  = (const float*)d_in[2];
    const float* a1s = (const float*)d_in[3];
    const float* a1d = (const float*)d_in[4];
    const float* b1  = (const float*)d_in[5];
    const float* W2  = (const float*)d_in[6];
    const float* a2s = (const float*)d_in[7];
    const float* a2d = (const float*)d_in[8];
    const float* b2  = (const float*)d_in[9];
    const float* W3  = (const float*)d_in[10];
    const float* a3s = (const float*)d_in[11];
    const float* a3d = (const float*)d_in[12];
    const float* b3  = (const float*)d_in[13];
    float* outp = (float*)d_out;

    const int N  = NN;
    const int E  = in_sizes[1] / 2;
    const int ET = E + N;
    const int B  = in_sizes[0] / (N * FIN);
    const int NB1024 = (N + 1023) / 1024;

    char* ws = (char*)d_ws;
    size_t off = 0;
    auto alloc = [&](size_t bytes) -> void* {
        void* p = ws + off;
        off += (bytes + 255) & ~(size_t)255;
        return p;
    };
    int* deg  = (int*)alloc((size_t)N * 4);
    int* rp   = (int*)alloc((size_t)(N + 1) * 4);
    int* wp   = (int*)alloc((size_t)N * 4);
    int* bsum = (int*)alloc(64 * 4);
    int* col  = (int*)alloc((size_t)ET * 4);

    size_t fused_need = off + ((size_t)N * B * HC * 2 + 256)      // h fp16
                            + ((size_t)N * B * HC * 4 + 256)      // z fp32
                            + 2 * ((size_t)N * B * 4 * 4 + 256);  // es/ed
    bool fused = (B == 4) && (ws_size >= fused_need);
    int BF = fused ? 4 : 1;

    __half* h  = (__half*)alloc((size_t)N * BF * HC * 2);
    float* z   = (float*)alloc((size_t)N * BF * HC * 4);
    float* es  = (float*)alloc((size_t)N * BF * 4 * 4);
    float* edv = (float*)alloc((size_t)N * BF * 4 * 4);

    // CSR build (graph shared by all batches/layers)
    init_deg_kernel<<<(N + 255) / 256, 256, 0, stream>>>(deg, N);
    hist_kernel<<<(E + 255) / 256, 256, 0, stream>>>(ei, deg, E);
    scan1_kernel<<<NB1024, 1024, 0, stream>>>(deg, rp, bsum, N);
    scan2_kernel<<<1, 64, 0, stream>>>(bsum, NB1024, rp, N);
    scan3_kernel<<<NB1024, 1024, 0, stream>>>(rp, wp, bsum, N);
    scatter_kernel<<<(ET + 255) / 256, 256, 0, stream>>>(ei, wp, col, E, N);

    if (fused) {
        dim3 g12((N + 63) / 64, 4);     // NT=64 (RN=4, G=16)
        dim3 g3((N + 127) / 128, 4);    // NT=128 (RN=2, G=4)
        int agg12 = (N * 4 * 4 + 255) / 256;
        int agg3  = (N * 4 + 255) / 256;
        gemm_kernel<128, 64, 4, 4, false><<<g12, 256, 0, stream>>>(x, W1, a1s, a1d, h, es, edv, N);
        agg_kernel<4, true, false, 4><<<agg12, 256, 0, stream>>>(rp, col, h, es, edv, b1, z, N);
        gemm_kernel<64, 64, 4, 4, true><<<g12, 256, 0, stream>>>(z, W2, a2s, a2d, h, es, edv, N);
        agg_kernel<4, true, false, 4><<<agg12, 256, 0, stream>>>(rp, col, h, es, edv, b2, z, N);
        gemm_kernel<64, 16, 2, 4, true><<<g3, 256, 0, stream>>>(z, W3, a3s, a3d, h, es, edv, N);
        agg_kernel<1, false, true, 4><<<agg3, 256, 0, stream>>>(rp, col, h, es, edv, b3, outp, N);
    } else {
        dim3 g12((N + 63) / 64, 1);
        dim3 g3((N + 127) / 128, 1);
        int agg12 = (N * 4 + 255) / 256;
        int agg3  = (N + 255) / 256;
        for (int b = 0; b < B; ++b) {
            const float* xb = x + (size_t)b * N * FIN;
            float* outb = outp + (size_t)b * N * NCLS;
            gemm_kernel<128, 64, 4, 1, false><<<g12, 256, 0, stream>>>(xb, W1, a1s, a1d, h, es, edv, N);
            agg_kernel<4, true, false, 1><<<agg12, 256, 0, stream>>>(rp, col, h, es, edv, b1, z, N);
            gemm_kernel<64, 64, 4, 1, false><<<g12, 256, 0, stream>>>(z, W2, a2s, a2d, h, es, edv, N);
            agg_kernel<4, true, false, 1><<<agg12, 256, 0, stream>>>(rp, col, h, es, edv, b2, z, N);
            gemm_kernel<64, 16, 2, 1, false><<<g3, 256, 0, stream>>>(z, W3, a3s, a3d, h, es, edv, N);
            agg_kernel<1, false, false, 1><<<agg3, 256, 0, stream>>>(rp, col, h, es, edv, b3, outb, N);
        }
    }
}